// Round 1
// 264.076 us; speedup vs baseline: 1.1025x; 1.1025x over previous
//
#include <hip/hip_runtime.h>
#include <hip/hip_bf16.h>

// QuantizedLinear: out[n][o] = scale[o] * dot(x[n,:], (q[o,:]-8)) + bias[o]
// R6 = R5 with the GEMM restructured from the m97-class 128x128 / 2-barrier
// loop (measured 911 TF, its known ~900 TF structural ceiling) to the 256x256
// 8-phase counted-vmcnt schedule (T1+T2+T3+T4+T5): 512 thr / 8 waves, BK=64,
// 128 KiB LDS double-buffered as {A0,A1,B0,B1} 128x64 half-tiles, one
// half-tile staged per phase with global_load_lds, single s_waitcnt vmcnt(4)
// per K-tile (never drained to 0 in the loop), raw s_barrier + lgkmcnt(0) +
// sched_barrier(0) per phase, setprio(1) around each 16-MFMA cluster.
// Kept verified pieces: chunk-XOR LDS swizzle (conflicts=0), pre-swizzled
// global source w/ linear LDS dest, C/D layout, fused scale/bias epilogue,
// prep kernel unchanged.

typedef __attribute__((ext_vector_type(8))) __bf16 bf16x8;
typedef __attribute__((ext_vector_type(4))) float f32x4;

#define GLOBAL_AS __attribute__((address_space(1)))
#define LDS_AS __attribute__((address_space(3)))

#define BM 256
#define BN 256
#define BK 64

__device__ inline unsigned short f32_to_bf16(float f) {
    unsigned int u = __float_as_uint(f);
    unsigned int r = (u + 0x7FFFu + ((u >> 16) & 1u)) >> 16;
    return (unsigned short)r;
}

// ---- merged preprocessing: x fp32 -> bf16 AND packed nibbles -> bf16 ints ----
__global__ void prep(const float* __restrict__ x, unsigned short* __restrict__ xb,
                     const int* __restrict__ wp, unsigned short* __restrict__ wb,
                     int n8x, int n4w) {
    const int stride = gridDim.x * blockDim.x;
    const int total = n8x + n4w;
    for (int i = blockIdx.x * blockDim.x + threadIdx.x; i < total; i += stride) {
        if (i < n8x) {
            float4 a = ((const float4*)x)[2 * i];
            float4 b = ((const float4*)x)[2 * i + 1];
            union { unsigned short h[8]; uint4 u; } o;
            o.h[0] = f32_to_bf16(a.x); o.h[1] = f32_to_bf16(a.y);
            o.h[2] = f32_to_bf16(a.z); o.h[3] = f32_to_bf16(a.w);
            o.h[4] = f32_to_bf16(b.x); o.h[5] = f32_to_bf16(b.y);
            o.h[6] = f32_to_bf16(b.z); o.h[7] = f32_to_bf16(b.w);
            ((uint4*)xb)[i] = o.u;
        } else {
            int k = i - n8x;
            int4 v = ((const int4*)wp)[k];
            int vals[4] = {v.x, v.y, v.z, v.w};
            union { unsigned short h[8]; uint4 u; } o;
#pragma unroll
            for (int t = 0; t < 4; ++t) {
                o.h[2 * t]     = f32_to_bf16((float)((vals[t] & 0xF) - 8));
                o.h[2 * t + 1] = f32_to_bf16((float)(((vals[t] >> 4) & 0xF) - 8));
            }
            ((uint4*)wb)[k] = o.u;
        }
    }
}

// ---- main GEMM: C[m][n] = sum_k A[m][k]*B[n][k]; epilogue scale/bias ----
// 256x256 tile, 8 waves. Wave (wm,wn) owns M-rows {16*(2i+wm)} i=0..7 and
// N-cols {16*(4j+wn)} j=0..3, so mh-halves/nh-halves map to LDS half-tiles
// uniformly across waves. LDS regions per 64KB buffer (ushort offsets):
// A0=0, A1=8192, B0=16384, B1=24576. Buffer stride 32768 ushorts.
template<int K, int N>
__global__ __launch_bounds__(512, 2) void gemm_bt(
    const unsigned short* __restrict__ A,
    const unsigned short* __restrict__ B,
    const float* __restrict__ scales,
    const float* __restrict__ bias,
    float* __restrict__ C,
    int GY)
{
    constexpr int NT = K / BK;   // 64 K-tiles
    __shared__ __align__(16) unsigned short lds[65536];  // 128 KiB

    const int tid  = threadIdx.x;
    const int wave = tid >> 6;
    const int lane = tid & 63;
    const int wm = wave >> 2;    // 0..1
    const int wn = wave & 3;     // 0..3

    // XCD swizzle: XCD x = bid&7 owns a contiguous sw-chunk -> a 2-column
    // stripe of the 16x16 block grid (B footprint 4MB = one XCD L2).
    const int bid = blockIdx.x;
    const int chunk = gridDim.x >> 3;
    const int sw = (bid & 7) * chunk + (bid >> 3);
    const int bx = sw / GY;
    const int by = sw - bx * GY;
    const int m0 = by * BM;
    const int n0 = bx * BN;

    // fragment LDS byte offsets (relative to a 64KB buffer base)
    const int am = lane & 15;
    const int aq = lane >> 4;
    const int cb = ((aq ^ (am & 7)) << 4);   // swizzled chunk byte, kk=0 (^64 for kk=1)

    int aoff[8], boff[4];
#pragma unroll
    for (int i = 0; i < 8; ++i) {
        int r = (2 * i + wm) * 16 + am;               // tile row 0..255
        aoff[i] = ((i < 4) ? 0 : 16384) + (r & 127) * 128 + cb;
    }
#pragma unroll
    for (int j = 0; j < 4; ++j) {
        int r = (4 * j + wn) * 16 + am;               // tile col 0..255
        boff[j] = 32768 + ((j < 2) ? 0 : 16384) + (r & 127) * 128 + cb;
    }

    // staging: half-tile = 128x64 bf16 = 1024 16B-chunks; thread covers flat
    // chunks tid and 512+tid. LDS dest linear; global source pre-swizzled.
    const int sch = tid & 7;
    const int r0 = tid >> 3;             // 0..63
    const int r1 = (512 + tid) >> 3;     // 64..127
    const size_t g0 = (size_t)r0 * K + (size_t)((sch ^ (r0 & 7)) * 8);
    const size_t g1 = (size_t)r1 * K + (size_t)((sch ^ (r1 & 7)) * 8);
    const int d0 = tid * 8;              // ushort units within region
    const int d1 = (512 + tid) * 8;

    const unsigned short* Abase = A + (size_t)m0 * K;
    const unsigned short* Bbase = B + (size_t)n0 * K;

    f32x4 acc[8][4];
#pragma unroll
    for (int i = 0; i < 8; ++i)
#pragma unroll
        for (int j = 0; j < 4; ++j)
            acc[i][j] = (f32x4){0.f, 0.f, 0.f, 0.f};

    const char* ldsB = (const char*)lds;
    bf16x8 af[4][2], bf[2][2];

#define STAGE(gbase, half, kcol, uoff)                                            \
    do {                                                                          \
        const unsigned short* _g = (gbase) + (size_t)((half) * 128) * K + (kcol); \
        __builtin_amdgcn_global_load_lds((const GLOBAL_AS void*)(_g + g0),        \
            (LDS_AS void*)(lds + (uoff) + d0), 16, 0, 0);                         \
        __builtin_amdgcn_global_load_lds((const GLOBAL_AS void*)(_g + g1),        \
            (LDS_AS void*)(lds + (uoff) + d1), 16, 0, 0);                         \
    } while (0)

#define LDA(mh, OB)                                                               \
    _Pragma("unroll") for (int i2 = 0; i2 < 4; ++i2) {                            \
        af[i2][0] = *(const bf16x8*)(ldsB + (OB) + aoff[(mh) * 4 + i2]);          \
        af[i2][1] = *(const bf16x8*)(ldsB + (OB) + (aoff[(mh) * 4 + i2] ^ 64));   \
    }

#define LDB(nh, OB)                                                               \
    _Pragma("unroll") for (int j2 = 0; j2 < 2; ++j2) {                            \
        bf[j2][0] = *(const bf16x8*)(ldsB + (OB) + boff[(nh) * 2 + j2]);          \
        bf[j2][1] = *(const bf16x8*)(ldsB + (OB) + (boff[(nh) * 2 + j2] ^ 64));   \
    }

#define BAR_LG()                                                                  \
    __builtin_amdgcn_s_barrier();                                                 \
    asm volatile("s_waitcnt lgkmcnt(0)" ::: "memory");                            \
    __builtin_amdgcn_sched_barrier(0)

#define MFMA_Q(mh, nh)                                                            \
    _Pragma("unroll") for (int i2 = 0; i2 < 4; ++i2)                              \
    _Pragma("unroll") for (int j2 = 0; j2 < 2; ++j2) {                            \
        acc[(mh) * 4 + i2][(nh) * 2 + j2] = __builtin_amdgcn_mfma_f32_16x16x32_bf16( \
            af[i2][0], bf[j2][0], acc[(mh) * 4 + i2][(nh) * 2 + j2], 0, 0, 0);    \
        acc[(mh) * 4 + i2][(nh) * 2 + j2] = __builtin_amdgcn_mfma_f32_16x16x32_bf16( \
            af[i2][1], bf[j2][1], acc[(mh) * 4 + i2][(nh) * 2 + j2], 0, 0, 0);    \
    }

// One K-tile = 4 phases (C-quadrants Q(0,0),(0,1),(1,1),(1,0)).
// Stage schedule (derived: each stage lands >= 1 phase after the last LDS
// read of the region it overwrites; vmcnt(4) at phase 4 leaves exactly the
// 2 newest half-tiles [A0(t+2),B1(t+2)] in flight across the boundary while
// guaranteeing tile t+1 is fully resident):
//   p1: B0(t+1)->other buf   p2: A1(t+1)->other buf
//   p3: A0(t+2)->this buf    p4: B1(t+2)->this buf, vmcnt(4)
#define GROUP(OB, OUS, OUSo, t)                                                   \
    {                                                                             \
        const int kn1 = (((t) + 1 < NT) ? (t) + 1 : NT - 1) * BK;                 \
        const int kn2 = (((t) + 2 < NT) ? (t) + 2 : NT - 1) * BK;                 \
        /* phase 1: Q(0,0) */                                                     \
        LDA(0, OB); LDB(0, OB);                                                   \
        STAGE(Bbase, 0, kn1, (OUSo) + 16384);                                     \
        BAR_LG();                                                                 \
        __builtin_amdgcn_s_setprio(1); MFMA_Q(0, 0); __builtin_amdgcn_s_setprio(0); \
        __builtin_amdgcn_s_barrier();                                             \
        /* phase 2: Q(0,1) */                                                     \
        LDB(1, OB);                                                               \
        STAGE(Abase, 1, kn1, (OUSo) + 8192);                                      \
        BAR_LG();                                                                 \
        __builtin_amdgcn_s_setprio(1); MFMA_Q(0, 1); __builtin_amdgcn_s_setprio(0); \
        __builtin_amdgcn_s_barrier();                                             \
        /* phase 3: Q(1,1) */                                                     \
        LDA(1, OB);                                                               \
        STAGE(Abase, 0, kn2, (OUS) + 0);                                          \
        BAR_LG();                                                                 \
        __builtin_amdgcn_s_setprio(1); MFMA_Q(1, 1); __builtin_amdgcn_s_setprio(0); \
        __builtin_amdgcn_s_barrier();                                             \
        /* phase 4: Q(1,0) */                                                     \
        LDB(0, OB);                                                               \
        STAGE(Bbase, 1, kn2, (OUS) + 24576);                                      \
        asm volatile("s_waitcnt vmcnt(4)" ::: "memory");                          \
        BAR_LG();                                                                 \
        __builtin_amdgcn_s_setprio(1); MFMA_Q(1, 0); __builtin_amdgcn_s_setprio(0); \
        __builtin_amdgcn_s_barrier();                                             \
    }

    // prologue: issue order matches steady state entering group 0:
    // A0(0), B1(0), B0(0), A1(0), A0(1), B1(1); vmcnt(4) leaves A0(1),B1(1)
    // in flight (counted, not drained).
    STAGE(Abase, 0, 0, 0);
    STAGE(Bbase, 1, 0, 24576);
    STAGE(Bbase, 0, 0, 16384);
    STAGE(Abase, 1, 0, 8192);
    STAGE(Abase, 0, BK, 32768);
    STAGE(Bbase, 1, BK, 32768 + 24576);
    asm volatile("s_waitcnt vmcnt(4)" ::: "memory");
    __builtin_amdgcn_s_barrier();

    for (int t = 0; t < NT; t += 2) {
        GROUP(0, 0, 32768, t);
        GROUP(65536, 32768, 0, t + 1);
    }

    // epilogue: C/D layout col=lane&15, row=(lane>>4)*4+reg
    const int cq = lane >> 4;
    const int cc = lane & 15;
#pragma unroll
    for (int j = 0; j < 4; ++j) {
        const int col = n0 + (4 * j + wn) * 16 + cc;
        const float s = scales[col];
        const float b = bias[col];
#pragma unroll
        for (int i = 0; i < 8; ++i) {
            const int rowb = m0 + (2 * i + wm) * 16 + cq * 4;
#pragma unroll
            for (int r = 0; r < 4; ++r) {
                C[(size_t)(rowb + r) * N + col] = acc[i][j][r] * s + b;
            }
        }
    }
#undef STAGE
#undef LDA
#undef LDB
#undef BAR_LG
#undef MFMA_Q
#undef GROUP
}

// ---- correctness fallback for unexpected shapes ----
__global__ void naive_kernel(const float* __restrict__ x, const int* __restrict__ wp,
                             const float* __restrict__ sc, const float* __restrict__ bs,
                             float* __restrict__ out, int NR, int OUTF, int INF) {
    int idx = blockIdx.x * 256 + threadIdx.x;
    if (idx >= NR * OUTF) return;
    int n = idx / OUTF, o = idx - n * OUTF;
    const float* xr = x + (size_t)n * INF;
    const int* wr = wp + (size_t)o * (INF / 2);
    float acc = 0.f;
    for (int c = 0; c < INF / 2; ++c) {
        int v = wr[c];
        acc += xr[2 * c] * (float)((v & 0xF) - 8) + xr[2 * c + 1] * (float)(((v >> 4) & 0xF) - 8);
    }
    out[idx] = acc * sc[o] + bs[o];
}

extern "C" void kernel_launch(void* const* d_in, const int* in_sizes, int n_in,
                              void* d_out, int out_size, void* d_ws, size_t ws_size,
                              hipStream_t stream) {
    const float* x      = (const float*)d_in[0];
    const int*   wp     = (const int*)d_in[1];
    const float* scales = (const float*)d_in[2];
    const float* bias   = (const float*)d_in[3];
    float* out = (float*)d_out;

    const int OUTF = in_sizes[2];
    const int INF  = (2 * in_sizes[1]) / OUTF;
    const int NR   = in_sizes[0] / INF;

    unsigned short* xb = (unsigned short*)d_ws;
    unsigned short* wb = xb + (size_t)NR * INF;
    const size_t need = ((size_t)NR * INF + (size_t)OUTF * INF) * sizeof(unsigned short);

    const int GX = OUTF / BN;
    const int GY = NR / BM;

    if (ws_size >= need && INF == 4096 && OUTF == 4096 && (NR % BM) == 0
        && ((GX * GY) % 8) == 0
        && (in_sizes[0] % 8) == 0 && (in_sizes[1] % 4) == 0) {
        prep<<<2048, 256, 0, stream>>>(x, xb, wp, wb, in_sizes[0] / 8, in_sizes[1] / 4);
        gemm_bt<4096, 4096><<<GX * GY, 512, 0, stream>>>(xb, wb, scales, bias, out, GY);
    } else {
        int total = NR * OUTF;
        naive_kernel<<<(total + 255) / 256, 256, 0, stream>>>(x, wp, scales, bias, out, NR, OUTF, INF);
    }
}